// Round 1
// baseline (319.358 us; speedup 1.0000x reference)
//
#include <hip/hip_runtime.h>
#include <hip/hip_bf16.h>

constexpr int kNodes = 50000;
constexpr int kEdges = 600000;
constexpr int kD     = 128;

// ---------------------------------------------------------------------------
// Kernel 1: dual GEMM.  hu = H @ U  (written straight into d_out),
//                       hv = H @ V  (written into workspace).
// One block = 16 rows of H staged in LDS; 128 threads, thread t owns column t
// of both outputs for all 16 rows.  k-loop unrolled by 4 so the LDS reads of
// the H tile become ds_read_b128 (broadcast, conflict-free).
// ---------------------------------------------------------------------------
__global__ __launch_bounds__(128) void gemm_dual(const float* __restrict__ H,
                                                 const float* __restrict__ U,
                                                 const float* __restrict__ V,
                                                 float* __restrict__ hu,
                                                 float* __restrict__ hv) {
    const int col = threadIdx.x;                  // 0..127
    const long row0 = (long)blockIdx.x * 16;

    __shared__ float hs[16][kD];
#pragma unroll
    for (int r = 0; r < 16; ++r)
        hs[r][col] = H[(row0 + r) * kD + col];
    __syncthreads();

    float aU[16], aV[16];
#pragma unroll
    for (int r = 0; r < 16; ++r) { aU[r] = 0.f; aV[r] = 0.f; }

    for (int k = 0; k < kD; k += 4) {
        float u[4], v[4];
#pragma unroll
        for (int j = 0; j < 4; ++j) {
            u[j] = U[(k + j) * kD + col];         // coalesced, L1/L2-resident
            v[j] = V[(k + j) * kD + col];
        }
#pragma unroll
        for (int r = 0; r < 16; ++r) {
            const float4 h4 = *reinterpret_cast<const float4*>(&hs[r][k]);
            aU[r] = fmaf(h4.x, u[0], aU[r]);  aV[r] = fmaf(h4.x, v[0], aV[r]);
            aU[r] = fmaf(h4.y, u[1], aU[r]);  aV[r] = fmaf(h4.y, v[1], aV[r]);
            aU[r] = fmaf(h4.z, u[2], aU[r]);  aV[r] = fmaf(h4.z, v[2], aV[r]);
            aU[r] = fmaf(h4.w, u[3], aU[r]);  aV[r] = fmaf(h4.w, v[3], aV[r]);
        }
    }

#pragma unroll
    for (int r = 0; r < 16; ++r) {
        hu[(row0 + r) * kD + col] = aU[r];
        hv[(row0 + r) * kD + col] = aV[r];
    }
}

// ---------------------------------------------------------------------------
// Kernel 2: edge scatter.  One 64-lane wave per edge; lane d handles elements
// d and d+64.  Index loads are wave-uniform (compiler emits scalar loads).
// out already holds H@U, so we accumulate the aggregation straight on top.
// ---------------------------------------------------------------------------
__global__ __launch_bounds__(256) void scatter_add(const float* __restrict__ hv,
                                                   const int* __restrict__ esrc,
                                                   const int* __restrict__ edst,
                                                   float* __restrict__ out) {
    const int wave = (int)((blockIdx.x * (long)blockDim.x + threadIdx.x) >> 6);
    const int lane = threadIdx.x & 63;
    if (wave >= kEdges) return;

    const int s = esrc[wave];
    const int t = edst[wave];
    const float* src = hv  + (size_t)s * kD;
    float*       dst = out + (size_t)t * kD;

    atomicAdd(&dst[lane],      src[lane]);
    atomicAdd(&dst[lane + 64], src[lane + 64]);
}

// ---------------------------------------------------------------------------
// Kernel 3: in-place vectorized ReLU over d_out.
// ---------------------------------------------------------------------------
__global__ __launch_bounds__(256) void relu_vec4(float4* __restrict__ out, int n4) {
    const int i = blockIdx.x * blockDim.x + threadIdx.x;
    if (i < n4) {
        float4 x = out[i];
        x.x = fmaxf(x.x, 0.f);
        x.y = fmaxf(x.y, 0.f);
        x.z = fmaxf(x.z, 0.f);
        x.w = fmaxf(x.w, 0.f);
        out[i] = x;
    }
}

extern "C" void kernel_launch(void* const* d_in, const int* in_sizes, int n_in,
                              void* d_out, int out_size, void* d_ws, size_t ws_size,
                              hipStream_t stream) {
    const float* H    = (const float*)d_in[0];
    const float* U    = (const float*)d_in[1];
    const float* V    = (const float*)d_in[2];
    const int*   esrc = (const int*)d_in[3];
    const int*   edst = (const int*)d_in[4];

    float* out = (float*)d_out;
    float* hv  = (float*)d_ws;     // 50000*128*4 = 25.6 MB scratch

    // 1) hu -> d_out, hv -> ws
    gemm_dual<<<kNodes / 16, 128, 0, stream>>>(H, U, V, out, hv);

    // 2) out += segment_sum(hv[src], dst): one wave per edge, 4 edges/block
    scatter_add<<<(kEdges + 3) / 4, 256, 0, stream>>>(hv, esrc, edst, out);

    // 3) out = relu(out)
    const int n4 = kNodes * kD / 4;
    relu_vec4<<<(n4 + 255) / 256, 256, 0, stream>>>((float4*)d_out, n4);
}

// Round 2
// 282.072 us; speedup vs baseline: 1.1322x; 1.1322x over previous
//
#include <hip/hip_runtime.h>
#include <hip/hip_bf16.h>

constexpr int kNodes = 50000;
constexpr int kEdges = 600000;
constexpr int kD     = 128;

// ---------------------------------------------------------------------------
// Kernel 1: dual GEMM.  hu = H @ U  (written straight into d_out),
//                       hv = H @ V  (written into workspace).  Unchanged from
// R1 (~65us); becomes the MFMA target next round.
// ---------------------------------------------------------------------------
__global__ __launch_bounds__(128) void gemm_dual(const float* __restrict__ H,
                                                 const float* __restrict__ U,
                                                 const float* __restrict__ V,
                                                 float* __restrict__ hu,
                                                 float* __restrict__ hv) {
    const int col = threadIdx.x;                  // 0..127
    const long row0 = (long)blockIdx.x * 16;

    __shared__ float hs[16][kD];
#pragma unroll
    for (int r = 0; r < 16; ++r)
        hs[r][col] = H[(row0 + r) * kD + col];
    __syncthreads();

    float aU[16], aV[16];
#pragma unroll
    for (int r = 0; r < 16; ++r) { aU[r] = 0.f; aV[r] = 0.f; }

    for (int k = 0; k < kD; k += 4) {
        float u[4], v[4];
#pragma unroll
        for (int j = 0; j < 4; ++j) {
            u[j] = U[(k + j) * kD + col];
            v[j] = V[(k + j) * kD + col];
        }
#pragma unroll
        for (int r = 0; r < 16; ++r) {
            const float4 h4 = *reinterpret_cast<const float4*>(&hs[r][k]);
            aU[r] = fmaf(h4.x, u[0], aU[r]);  aV[r] = fmaf(h4.x, v[0], aV[r]);
            aU[r] = fmaf(h4.y, u[1], aU[r]);  aV[r] = fmaf(h4.y, v[1], aV[r]);
            aU[r] = fmaf(h4.z, u[2], aU[r]);  aV[r] = fmaf(h4.z, v[2], aV[r]);
            aU[r] = fmaf(h4.w, u[3], aU[r]);  aV[r] = fmaf(h4.w, v[3], aV[r]);
        }
    }

#pragma unroll
    for (int r = 0; r < 16; ++r) {
        hu[(row0 + r) * kD + col] = aU[r];
        hv[(row0 + r) * kD + col] = aV[r];
    }
}

// ---------------------------------------------------------------------------
// CSR build step A: histogram of edge destinations.  (cnt pre-zeroed by
// hipMemsetAsync.)  600K int atomics over 50K counters -> few us.
// ---------------------------------------------------------------------------
__global__ __launch_bounds__(256) void edge_hist(const int* __restrict__ edst,
                                                 int* __restrict__ cnt) {
    const int e = blockIdx.x * blockDim.x + threadIdx.x;
    if (e < kEdges) atomicAdd(&cnt[edst[e]], 1);
}

// ---------------------------------------------------------------------------
// CSR build step B: exclusive scan of cnt -> offs (and a second copy `cursor`
// used as the running fill pointer).  Single 1024-thread block; each thread
// owns 49 consecutive counters (serial sum), one 10-step Hillis-Steele block
// scan over the 1024 partials, then serial write-out.  ~5-10us.
// ---------------------------------------------------------------------------
__global__ __launch_bounds__(1024) void scan_offsets(const int* __restrict__ cnt,
                                                     int* __restrict__ offs,
                                                     int* __restrict__ cursor) {
    constexpr int PER = (kNodes + 1023) / 1024;   // 49
    const int start = threadIdx.x * PER;
    const int end   = min(start + PER, kNodes);

    int sum = 0;
    for (int i = start; i < end; ++i) sum += cnt[i];

    __shared__ int buf[1024];
    buf[threadIdx.x] = sum;
    __syncthreads();
#pragma unroll
    for (int d = 1; d < 1024; d <<= 1) {
        int t = (threadIdx.x >= d) ? buf[threadIdx.x - d] : 0;
        __syncthreads();
        buf[threadIdx.x] += t;
        __syncthreads();
    }

    int run = buf[threadIdx.x] - sum;             // exclusive prefix
    for (int i = start; i < end; ++i) {
        offs[i]   = run;
        cursor[i] = run;
        run += cnt[i];
    }
    if (threadIdx.x == 1023) offs[kNodes] = buf[1023];  // = kEdges
}

// ---------------------------------------------------------------------------
// CSR build step C: drop each edge's SOURCE id into its destination's segment.
// (Stores src directly -- removes one indirection from the hot aggregate loop.)
// ---------------------------------------------------------------------------
__global__ __launch_bounds__(256) void fill_csr(const int* __restrict__ esrc,
                                                const int* __restrict__ edst,
                                                int* __restrict__ cursor,
                                                int* __restrict__ csr_src) {
    const int e = blockIdx.x * blockDim.x + threadIdx.x;
    if (e < kEdges) {
        const int slot = atomicAdd(&cursor[edst[e]], 1);
        csr_src[slot] = esrc[e];
    }
}

// ---------------------------------------------------------------------------
// Kernel 2': aggregation, atomic-free.  One 64-lane wave per node; lane d owns
// features d and d+64.  Neighbor indices are wave-uniform -> hoisted to SGPR
// via readfirstlane so row loads are scalar-base + lane-offset (coalesced).
// 2-edge unroll for load ILP.  ReLU + (H@U) add fused into the single write.
// ---------------------------------------------------------------------------
__global__ __launch_bounds__(256) void aggregate_relu(const float* __restrict__ hv,
                                                      const int* __restrict__ offs,
                                                      const int* __restrict__ csr_src,
                                                      float* __restrict__ out) {
    const int wid  = (int)((blockIdx.x * (long)blockDim.x + threadIdx.x) >> 6);
    const int lane = threadIdx.x & 63;
    if (wid >= kNodes) return;

    const int beg = offs[wid];
    const int end = offs[wid + 1];

    float a0 = 0.f, a1 = 0.f;
    int e = beg;
    for (; e + 1 < end; e += 2) {
        const int s0 = __builtin_amdgcn_readfirstlane(csr_src[e]);
        const int s1 = __builtin_amdgcn_readfirstlane(csr_src[e + 1]);
        const float* r0 = hv + (size_t)s0 * kD;
        const float* r1 = hv + (size_t)s1 * kD;
        const float x0 = r0[lane], y0 = r0[lane + 64];
        const float x1 = r1[lane], y1 = r1[lane + 64];
        a0 += x0 + x1;
        a1 += y0 + y1;
    }
    if (e < end) {
        const int s = __builtin_amdgcn_readfirstlane(csr_src[e]);
        a0 += hv[(size_t)s * kD + lane];
        a1 += hv[(size_t)s * kD + lane + 64];
    }

    const size_t o = (size_t)wid * kD + lane;
    out[o]      = fmaxf(out[o]      + a0, 0.f);
    out[o + 64] = fmaxf(out[o + 64] + a1, 0.f);
}

// ---------------------------------------------------------------------------
// Fallback (ws too small for CSR): R1's atomic scatter + relu.
// ---------------------------------------------------------------------------
__global__ __launch_bounds__(256) void scatter_add(const float* __restrict__ hv,
                                                   const int* __restrict__ esrc,
                                                   const int* __restrict__ edst,
                                                   float* __restrict__ out) {
    const int wave = (int)((blockIdx.x * (long)blockDim.x + threadIdx.x) >> 6);
    const int lane = threadIdx.x & 63;
    if (wave >= kEdges) return;
    const int s = esrc[wave];
    const int t = edst[wave];
    const float* src = hv  + (size_t)s * kD;
    float*       dst = out + (size_t)t * kD;
    atomicAdd(&dst[lane],      src[lane]);
    atomicAdd(&dst[lane + 64], src[lane + 64]);
}

__global__ __launch_bounds__(256) void relu_vec4(float4* __restrict__ out, int n4) {
    const int i = blockIdx.x * blockDim.x + threadIdx.x;
    if (i < n4) {
        float4 x = out[i];
        x.x = fmaxf(x.x, 0.f); x.y = fmaxf(x.y, 0.f);
        x.z = fmaxf(x.z, 0.f); x.w = fmaxf(x.w, 0.f);
        out[i] = x;
    }
}

extern "C" void kernel_launch(void* const* d_in, const int* in_sizes, int n_in,
                              void* d_out, int out_size, void* d_ws, size_t ws_size,
                              hipStream_t stream) {
    const float* H    = (const float*)d_in[0];
    const float* U    = (const float*)d_in[1];
    const float* V    = (const float*)d_in[2];
    const int*   esrc = (const int*)d_in[3];
    const int*   edst = (const int*)d_in[4];

    float* out = (float*)d_out;

    // Workspace layout
    const size_t hv_bytes = (size_t)kNodes * kD * sizeof(float);   // 25.6 MB
    char* p = (char*)d_ws;
    float* hv      = (float*)p;                 p += hv_bytes;
    int*   cnt     = (int*)p;                   p += (size_t)kNodes * sizeof(int);
    int*   offs    = (int*)p;                   p += (size_t)(kNodes + 1) * sizeof(int);
    int*   cursor  = (int*)p;                   p += (size_t)kNodes * sizeof(int);
    int*   csr_src = (int*)p;                   p += (size_t)kEdges * sizeof(int);
    const size_t needed = (size_t)(p - (char*)d_ws);

    // 1) hu -> d_out, hv -> ws
    gemm_dual<<<kNodes / 16, 128, 0, stream>>>(H, U, V, out, hv);

    if (ws_size >= needed) {
        // 2) CSR build: histogram -> scan -> fill
        hipMemsetAsync(cnt, 0, (size_t)kNodes * sizeof(int), stream);
        edge_hist<<<(kEdges + 255) / 256, 256, 0, stream>>>(edst, cnt);
        scan_offsets<<<1, 1024, 0, stream>>>(cnt, offs, cursor);
        fill_csr<<<(kEdges + 255) / 256, 256, 0, stream>>>(esrc, edst, cursor, csr_src);

        // 3) out = relu(out + segment_sum(hv[src], dst)), one wave per node
        aggregate_relu<<<(kNodes * 64 + 255) / 256, 256, 0, stream>>>(hv, offs, csr_src, out);
    } else {
        // Fallback: atomic scatter (R1 path)
        scatter_add<<<(kEdges + 3) / 4, 256, 0, stream>>>(hv, esrc, edst, out);
        const int n4 = kNodes * kD / 4;
        relu_vec4<<<(n4 + 255) / 256, 256, 0, stream>>>((float4*)d_out, n4);
    }
}

// Round 3
// 170.694 us; speedup vs baseline: 1.8709x; 1.6525x over previous
//
#include <hip/hip_runtime.h>
#include <hip/hip_bf16.h>

constexpr int kNodes = 50000;
constexpr int kEdges = 600000;
constexpr int kD     = 128;
constexpr int kStrips = kNodes / 16;          // 3125 exactly

typedef __attribute__((ext_vector_type(8))) short  short8;   // 8 bf16 (A/B frag)
typedef __attribute__((ext_vector_type(4))) float  f32x4;    // C/D frag

__device__ __forceinline__ short f2bf(float x) {
    __hip_bfloat16 h = __float2bfloat16(x);                   // RTNE
    return __builtin_bit_cast(short, h);
}

// ---------------------------------------------------------------------------
// Prep: pack B^T = [U | V]^T as bf16, BT[n][k], n in [0,256), k in [0,128).
// Row n of BT is column n of U (n<128) or V (n-128).  64 KB, L2-resident.
// ---------------------------------------------------------------------------
__global__ __launch_bounds__(128) void pack_b(const float* __restrict__ U,
                                              const float* __restrict__ V,
                                              short* __restrict__ BT) {
    const int n = blockIdx.x;        // 0..255
    const int k = threadIdx.x;       // 0..127
    const float x = (n < kD) ? U[k * kD + n] : V[k * kD + (n - kD)];
    BT[n * kD + k] = f2bf(x);
}

// ---------------------------------------------------------------------------
// Kernel 1: MFMA dual GEMM.  One wave per 16-row strip of H; 16 n-tiles
// (cols 0-127 -> hu=d_out f32, cols 128-255 -> hv ws bf16).  A fragments are
// read from f32 H and converted in-register (H read exactly once).
// mfma_f32_16x16x32_bf16: A lane m=l&15, k-octet=l>>4 (8 contiguous k);
// C/D: col=l&15, row=(l>>4)*4+j.
// ---------------------------------------------------------------------------
__global__ __launch_bounds__(256) void gemm_mfma(const float* __restrict__ H,
                                                 const short* __restrict__ BT,
                                                 float* __restrict__ hu,
                                                 unsigned short* __restrict__ hvb) {
    const int wid = (int)((blockIdx.x * (long)blockDim.x + threadIdx.x) >> 6);
    if (wid >= kStrips) return;
    const int lane = threadIdx.x & 63;
    const int m  = lane & 15;
    const int kg = lane >> 4;                      // 0..3
    const long row0 = (long)wid * 16;

    const float* hrow = H + (row0 + m) * kD + kg * 8;

    f32x4 acc[16];
#pragma unroll
    for (int i = 0; i < 16; ++i) acc[i] = (f32x4){0.f, 0.f, 0.f, 0.f};

#pragma unroll
    for (int t = 0; t < 4; ++t) {                  // K steps of 32
        const float4 f0 = *reinterpret_cast<const float4*>(hrow + t * 32);
        const float4 f1 = *reinterpret_cast<const float4*>(hrow + t * 32 + 4);
        short8 a;
        a[0] = f2bf(f0.x); a[1] = f2bf(f0.y); a[2] = f2bf(f0.z); a[3] = f2bf(f0.w);
        a[4] = f2bf(f1.x); a[5] = f2bf(f1.y); a[6] = f2bf(f1.z); a[7] = f2bf(f1.w);

        const short* bbase = BT + (size_t)m * kD + t * 32 + kg * 8;
#pragma unroll
        for (int nt = 0; nt < 16; ++nt) {
            const short8 b = *reinterpret_cast<const short8*>(bbase + (size_t)nt * 16 * kD);
            acc[nt] = __builtin_amdgcn_mfma_f32_16x16x32_bf16(a, b, acc[nt], 0, 0, 0);
        }
    }

#pragma unroll
    for (int nt = 0; nt < 8; ++nt) {               // hu -> d_out (f32)
        const int c = nt * 16 + m;
#pragma unroll
        for (int j = 0; j < 4; ++j)
            hu[(row0 + kg * 4 + j) * kD + c] = acc[nt][j];
    }
#pragma unroll
    for (int nt = 8; nt < 16; ++nt) {              // hv -> ws (bf16)
        const int c = (nt - 8) * 16 + m;
#pragma unroll
        for (int j = 0; j < 4; ++j)
            hvb[(row0 + kg * 4 + j) * kD + c] = (unsigned short)f2bf(acc[nt][j]);
    }
}

// ---------------------------------------------------------------------------
// CSR step A: histogram of destinations (cnt pre-zeroed via memsetAsync).
// ---------------------------------------------------------------------------
__global__ __launch_bounds__(256) void edge_hist(const int* __restrict__ edst,
                                                 int* __restrict__ cnt) {
    const int e = blockIdx.x * blockDim.x + threadIdx.x;
    if (e < kEdges) atomicAdd(&cnt[edst[e]], 1);
}

// ---------------------------------------------------------------------------
// CSR step B: segment allocation WITHOUT a grid-serial scan.  Segments need
// to be contiguous, not node-ordered: wave prefix-scan of counts + ONE
// atomicAdd on a global cursor per wave (781 wave-atomics total).
// ---------------------------------------------------------------------------
__global__ __launch_bounds__(256) void alloc_slots(const int* __restrict__ cnt,
                                                   int* __restrict__ offs,
                                                   int* __restrict__ cursor,
                                                   int* __restrict__ total) {
    const int i = blockIdx.x * blockDim.x + threadIdx.x;
    const int lane = threadIdx.x & 63;
    const int c = (i < kNodes) ? cnt[i] : 0;
    int incl = c;
#pragma unroll
    for (int d = 1; d < 64; d <<= 1) {
        const int t = __shfl_up(incl, d, 64);
        if (lane >= d) incl += t;
    }
    int base = 0;
    if (lane == 63) base = atomicAdd(total, incl); // incl @ lane63 = wave sum
    base = __shfl(base, 63, 64);
    if (i < kNodes) {
        const int o = base + incl - c;             // exclusive within wave
        offs[i]   = o;
        cursor[i] = o;
    }
}

// ---------------------------------------------------------------------------
// CSR step C: drop each edge's SOURCE id into its destination's segment.
// ---------------------------------------------------------------------------
__global__ __launch_bounds__(256) void fill_csr(const int* __restrict__ esrc,
                                                const int* __restrict__ edst,
                                                int* __restrict__ cursor,
                                                int* __restrict__ csr_src) {
    const int e = blockIdx.x * blockDim.x + threadIdx.x;
    if (e < kEdges) {
        const int slot = atomicAdd(&cursor[edst[e]], 1);
        csr_src[slot] = esrc[e];
    }
}

// ---------------------------------------------------------------------------
// Kernel 2: aggregation + ReLU.  One wave per node; hv rows are bf16 so each
// lane loads ONE dword per neighbor row (features 2*lane, 2*lane+1) and
// expands to f32 via bit-shift (exact).  out already holds hu (f32).
// ---------------------------------------------------------------------------
__global__ __launch_bounds__(256) void aggregate_relu(const unsigned int* __restrict__ hvb,
                                                      const int* __restrict__ offs,
                                                      const int* __restrict__ cnt,
                                                      const int* __restrict__ csr_src,
                                                      float* __restrict__ out) {
    const int wid  = (int)((blockIdx.x * (long)blockDim.x + threadIdx.x) >> 6);
    const int lane = threadIdx.x & 63;
    if (wid >= kNodes) return;

    const int beg = offs[wid];
    const int end = beg + cnt[wid];

    float a0 = 0.f, a1 = 0.f;
    int e = beg;
    for (; e + 1 < end; e += 2) {
        const int s0 = __builtin_amdgcn_readfirstlane(csr_src[e]);
        const int s1 = __builtin_amdgcn_readfirstlane(csr_src[e + 1]);
        const unsigned int w0 = hvb[(size_t)s0 * 64 + lane];
        const unsigned int w1 = hvb[(size_t)s1 * 64 + lane];
        a0 += __uint_as_float(w0 << 16) + __uint_as_float(w1 << 16);
        a1 += __uint_as_float(w0 & 0xffff0000u) + __uint_as_float(w1 & 0xffff0000u);
    }
    if (e < end) {
        const int s = __builtin_amdgcn_readfirstlane(csr_src[e]);
        const unsigned int w = hvb[(size_t)s * 64 + lane];
        a0 += __uint_as_float(w << 16);
        a1 += __uint_as_float(w & 0xffff0000u);
    }

    float2* out2 = reinterpret_cast<float2*>(out);
    float2 o = out2[(size_t)wid * 64 + lane];
    o.x = fmaxf(o.x + a0, 0.f);
    o.y = fmaxf(o.y + a1, 0.f);
    out2[(size_t)wid * 64 + lane] = o;
}

extern "C" void kernel_launch(void* const* d_in, const int* in_sizes, int n_in,
                              void* d_out, int out_size, void* d_ws, size_t ws_size,
                              hipStream_t stream) {
    const float* H    = (const float*)d_in[0];
    const float* U    = (const float*)d_in[1];
    const float* V    = (const float*)d_in[2];
    const int*   esrc = (const int*)d_in[3];
    const int*   edst = (const int*)d_in[4];

    float* out = (float*)d_out;

    // Workspace layout (~15.9 MB; R2 path used 28.4 MB and passed)
    char* p = (char*)d_ws;
    unsigned short* hvb = (unsigned short*)p;  p += (size_t)kNodes * kD * 2;  // 12.8 MB
    short* BT           = (short*)p;           p += (size_t)256 * kD * 2;     // 64 KB
    int*   cnt          = (int*)p;             p += (size_t)kNodes * 4;
    int*   total        = (int*)p;             p += 4;                        // memset with cnt
    int*   offs         = (int*)p;             p += (size_t)kNodes * 4;
    int*   cursor       = (int*)p;             p += (size_t)kNodes * 4;
    int*   csr_src      = (int*)p;             p += (size_t)kEdges * 4;

    // zero cnt + total in one shot
    hipMemsetAsync(cnt, 0, ((size_t)kNodes + 1) * sizeof(int), stream);

    // B pack + dual MFMA GEMM (hu -> d_out, hv -> ws as bf16)
    pack_b<<<256, 128, 0, stream>>>(U, V, BT);
    gemm_mfma<<<(kStrips * 64 + 255) / 256, 256, 0, stream>>>(H, BT, out, hvb);

    // CSR build: histogram -> wave-atomic segment alloc -> fill
    edge_hist<<<(kEdges + 255) / 256, 256, 0, stream>>>(edst, cnt);
    alloc_slots<<<(kNodes + 255) / 256, 256, 0, stream>>>(cnt, offs, cursor, total);
    fill_csr<<<(kEdges + 255) / 256, 256, 0, stream>>>(esrc, edst, cursor, csr_src);

    // Aggregate + fused ReLU
    aggregate_relu<<<(kNodes * 64 + 255) / 256, 256, 0, stream>>>(
        (const unsigned int*)hvb, offs, cnt, csr_src, out);
}

// Round 4
// 115.650 us; speedup vs baseline: 2.7614x; 1.4759x over previous
//
#include <hip/hip_runtime.h>
#include <hip/hip_bf16.h>

constexpr int kNodes  = 50000;
constexpr int kEdges  = 600000;
constexpr int kD      = 128;
constexpr int kStrips = kNodes / 16;     // 3125 exactly
constexpr int kStride = 64;              // fixed CSR segment capacity (max deg ~35)

typedef __attribute__((ext_vector_type(8))) short  short8;   // 8 bf16 (A/B frag)
typedef __attribute__((ext_vector_type(4))) float  f32x4;    // C/D frag

__device__ __forceinline__ short f2bf(float x) {
    __hip_bfloat16 h = __float2bfloat16(x);                   // RTNE
    return __builtin_bit_cast(short, h);
}

// ---------------------------------------------------------------------------
// Prep: pack B^T = [U | V]^T as bf16, BT[n][k], n in [0,256), k in [0,128).
// ---------------------------------------------------------------------------
__global__ __launch_bounds__(128) void pack_b(const float* __restrict__ U,
                                              const float* __restrict__ V,
                                              short* __restrict__ BT) {
    const int n = blockIdx.x;        // 0..255
    const int k = threadIdx.x;       // 0..127
    const float x = (n < kD) ? U[k * kD + n] : V[k * kD + (n - kD)];
    BT[n * kD + k] = f2bf(x);
}

// ---------------------------------------------------------------------------
// Kernel 1: MFMA dual GEMM, latency-optimized: wave = 16 rows x 64 cols
// (4 n-tiles, acc = 16 VGPRs).  Block = 1 strip x 4 col-quarters -> 3125
// blocks = 12 blocks/CU -> occupancy hits the 32-wave/CU cap (vs 19% in R3).
// Quarters 0,1 -> hu (f32, d_out); quarters 2,3 -> hv (bf16, ws).
// mfma_f32_16x16x32_bf16: A lane m=l&15 reads 8 contiguous k at octet l>>4;
// C/D: col=l&15, row=(l>>4)*4+j  (m89-verified mapping).
// ---------------------------------------------------------------------------
__global__ __launch_bounds__(256) void gemm_mfma(const float* __restrict__ H,
                                                 const short* __restrict__ BT,
                                                 float* __restrict__ hu,
                                                 unsigned short* __restrict__ hvb) {
    const int strip = blockIdx.x;               // 0..3124
    const int quad  = threadIdx.x >> 6;         // 0..3 (64-col quarter)
    const int lane  = threadIdx.x & 63;
    const int m  = lane & 15;
    const int kg = lane >> 4;                   // 0..3
    const long row0 = (long)strip * 16;

    const float* hrow = H + (row0 + m) * kD + kg * 8;

    f32x4 acc[4];
#pragma unroll
    for (int i = 0; i < 4; ++i) acc[i] = (f32x4){0.f, 0.f, 0.f, 0.f};

#pragma unroll
    for (int t = 0; t < 4; ++t) {               // K steps of 32
        const float4 f0 = *reinterpret_cast<const float4*>(hrow + t * 32);
        const float4 f1 = *reinterpret_cast<const float4*>(hrow + t * 32 + 4);
        short8 a;
        a[0] = f2bf(f0.x); a[1] = f2bf(f0.y); a[2] = f2bf(f0.z); a[3] = f2bf(f0.w);
        a[4] = f2bf(f1.x); a[5] = f2bf(f1.y); a[6] = f2bf(f1.z); a[7] = f2bf(f1.w);

        // B row for global col c is BT row c;  c = quad*64 + n*16 + m
        const short* bbase = BT + ((size_t)quad * 64 + m) * kD + t * 32 + kg * 8;
#pragma unroll
        for (int n = 0; n < 4; ++n) {
            const short8 b = *reinterpret_cast<const short8*>(bbase + (size_t)n * 16 * kD);
            acc[n] = __builtin_amdgcn_mfma_f32_16x16x32_bf16(a, b, acc[n], 0, 0, 0);
        }
    }

    if (quad < 2) {                             // hu -> d_out (f32)
#pragma unroll
        for (int n = 0; n < 4; ++n) {
            const int c = quad * 64 + n * 16 + m;
#pragma unroll
            for (int j = 0; j < 4; ++j)
                hu[(row0 + kg * 4 + j) * kD + c] = acc[n][j];
        }
    } else {                                    // hv -> ws (bf16)
#pragma unroll
        for (int n = 0; n < 4; ++n) {
            const int c = (quad - 2) * 64 + n * 16 + m;
#pragma unroll
            for (int j = 0; j < 4; ++j)
                hvb[(row0 + kg * 4 + j) * kD + c] = (unsigned short)f2bf(acc[n][j]);
        }
    }
}

// ---------------------------------------------------------------------------
// CSR build, single pass: fixed-stride segments.  slot = atomicAdd(cursor[dst])
// allocates directly; cursor doubles as the per-node count.  (cursor pre-
// zeroed by hipMemsetAsync.)  Clamp guards ws (never triggers: max deg ~35.)
// ---------------------------------------------------------------------------
__global__ __launch_bounds__(256) void fill_csr(const int* __restrict__ esrc,
                                                const int* __restrict__ edst,
                                                int* __restrict__ cursor,
                                                int* __restrict__ csr_src) {
    const int e = blockIdx.x * blockDim.x + threadIdx.x;
    if (e < kEdges) {
        const int d = edst[e];
        const int slot = atomicAdd(&cursor[d], 1);
        if (slot < kStride) csr_src[(size_t)d * kStride + slot] = esrc[e];
    }
}

// ---------------------------------------------------------------------------
// Kernel 2: aggregation + ReLU.  One wave per node.  The whole neighbor list
// is fetched with ONE per-lane vector load (seg[lane]); readlane broadcasts
// each index (uniform loop var -> SGPR).  Unroll x4 for MLP.  hv rows are
// bf16: each lane loads one dword (features 2*lane, 2*lane+1), expands to f32
// by bit-shift (exact).  out already holds hu (f32); ReLU fused.
// ---------------------------------------------------------------------------
__global__ __launch_bounds__(256) void aggregate_relu(const unsigned int* __restrict__ hvb,
                                                      const int* __restrict__ cursor,
                                                      const int* __restrict__ csr_src,
                                                      float* __restrict__ out) {
    const int wid  = (int)((blockIdx.x * (long)blockDim.x + threadIdx.x) >> 6);
    const int lane = threadIdx.x & 63;
    if (wid >= kNodes) return;

    const int deg = min(cursor[wid], kStride);          // wave-uniform
    const int v   = csr_src[(size_t)wid * kStride + lane];  // whole list, 1 load

    float a0 = 0.f, a1 = 0.f;
    int e = 0;
    for (; e + 4 <= deg; e += 4) {
        const int s0 = __builtin_amdgcn_readlane(v, e);
        const int s1 = __builtin_amdgcn_readlane(v, e + 1);
        const int s2 = __builtin_amdgcn_readlane(v, e + 2);
        const int s3 = __builtin_amdgcn_readlane(v, e + 3);
        const unsigned int w0 = hvb[(size_t)s0 * 64 + lane];
        const unsigned int w1 = hvb[(size_t)s1 * 64 + lane];
        const unsigned int w2 = hvb[(size_t)s2 * 64 + lane];
        const unsigned int w3 = hvb[(size_t)s3 * 64 + lane];
        a0 += __uint_as_float(w0 << 16) + __uint_as_float(w1 << 16)
            + __uint_as_float(w2 << 16) + __uint_as_float(w3 << 16);
        a1 += __uint_as_float(w0 & 0xffff0000u) + __uint_as_float(w1 & 0xffff0000u)
            + __uint_as_float(w2 & 0xffff0000u) + __uint_as_float(w3 & 0xffff0000u);
    }
    for (; e < deg; ++e) {
        const int s = __builtin_amdgcn_readlane(v, e);
        const unsigned int w = hvb[(size_t)s * 64 + lane];
        a0 += __uint_as_float(w << 16);
        a1 += __uint_as_float(w & 0xffff0000u);
    }

    float2* out2 = reinterpret_cast<float2*>(out);
    float2 o = out2[(size_t)wid * 64 + lane];
    o.x = fmaxf(o.x + a0, 0.f);
    o.y = fmaxf(o.y + a1, 0.f);
    out2[(size_t)wid * 64 + lane] = o;
}

extern "C" void kernel_launch(void* const* d_in, const int* in_sizes, int n_in,
                              void* d_out, int out_size, void* d_ws, size_t ws_size,
                              hipStream_t stream) {
    const float* H    = (const float*)d_in[0];
    const float* U    = (const float*)d_in[1];
    const float* V    = (const float*)d_in[2];
    const int*   esrc = (const int*)d_in[3];
    const int*   edst = (const int*)d_in[4];

    float* out = (float*)d_out;

    // Workspace layout (~25.9 MB; 28.4 MB was available in R2)
    char* p = (char*)d_ws;
    unsigned short* hvb = (unsigned short*)p;  p += (size_t)kNodes * kD * 2;        // 12.8 MB
    short* BT           = (short*)p;           p += (size_t)256 * kD * 2;           // 64 KB
    int*   cursor       = (int*)p;             p += (size_t)kNodes * 4;             // 200 KB
    int*   csr_src      = (int*)p;             p += (size_t)kNodes * kStride * 4;   // 12.8 MB

    hipMemsetAsync(cursor, 0, (size_t)kNodes * sizeof(int), stream);

    // B pack + dual MFMA GEMM (hu -> d_out, hv -> ws as bf16)
    pack_b<<<256, 128, 0, stream>>>(U, V, BT);
    gemm_mfma<<<kStrips, 256, 0, stream>>>(H, BT, out, hvb);

    // CSR build: single fixed-stride scatter
    fill_csr<<<(kEdges + 255) / 256, 256, 0, stream>>>(esrc, edst, cursor, csr_src);

    // Aggregate + fused ReLU
    aggregate_relu<<<(kNodes * 64 + 255) / 256, 256, 0, stream>>>(
        (const unsigned int*)hvb, cursor, csr_src, out);
}

// Round 5
// 103.908 us; speedup vs baseline: 3.0735x; 1.1130x over previous
//
#include <hip/hip_runtime.h>
#include <hip/hip_bf16.h>

constexpr int kNodes  = 50000;
constexpr int kEdges  = 600000;
constexpr int kD      = 128;
constexpr int kStrips = kNodes / 16;               // 3125 gemm blocks
constexpr int kStride = 64;                        // CSR segment capacity (max deg ~35)
constexpr int kFillBlocks = (kEdges + 255) / 256;  // 2344 fill blocks
constexpr int kPairBlocks = 2 * kFillBlocks;       // 4688 interleaved region
constexpr int kTotalBlocks = kStrips + kFillBlocks;// 5469

typedef __attribute__((ext_vector_type(8))) short  short8;   // 8 bf16 (A/B frag)
typedef __attribute__((ext_vector_type(4))) float  f32x4;    // C/D frag

__device__ __forceinline__ short f2bf(float x) {
    __hip_bfloat16 h = __float2bfloat16(x);                   // RTNE
    return __builtin_bit_cast(short, h);
}

// ---------------------------------------------------------------------------
// Prep: pack B^T = [U | V]^T as bf16, BT[n][k], n in [0,256), k in [0,128).
// ---------------------------------------------------------------------------
__global__ __launch_bounds__(128) void pack_b(const float* __restrict__ U,
                                              const float* __restrict__ V,
                                              short* __restrict__ BT) {
    const int n = blockIdx.x;        // 0..255
    const int k = threadIdx.x;       // 0..127
    const float x = (n < kD) ? U[k * kD + n] : V[k * kD + (n - kD)];
    BT[n * kD + k] = f2bf(x);
}

// ---------------------------------------------------------------------------
// FUSED kernel: gemm (MFMA dual GEMM) + fill (CSR scatter).  The two jobs
// have disjoint in/out sets -> safe to run in one dispatch.  Both are
// latency-bound on DIFFERENT resources (HBM+MFMA vs L2 atomics); block-level
// interleaving (even=fill, odd=gemm over the paired region) makes their
// stalls hide each other instead of serializing 48us + 48us.
//
// gemm role: wave = 16 rows x 64 cols (4 n-tiles).  Quarters 0,1 -> hu
// (f32, d_out); quarters 2,3 -> hv (bf16, ws).
// mfma_f32_16x16x32_bf16: A lane m=l&15 reads 8 contiguous k at octet l>>4;
// C/D: col=l&15, row=(l>>4)*4+j  (m89-verified mapping).
//
// fill role: slot = atomicAdd(&cursor[dst],1); csr_src[dst*64+slot] = src.
// cursor doubles as the per-node degree (pre-zeroed by hipMemsetAsync).
// ---------------------------------------------------------------------------
__global__ __launch_bounds__(256) void gemm_fill(const float* __restrict__ H,
                                                 const short* __restrict__ BT,
                                                 const int* __restrict__ esrc,
                                                 const int* __restrict__ edst,
                                                 float* __restrict__ hu,
                                                 unsigned short* __restrict__ hvb,
                                                 int* __restrict__ cursor,
                                                 int* __restrict__ csr_src) {
    const int bid = blockIdx.x;

    if (bid < kPairBlocks && (bid & 1)) {
        // ---- fill role: 256 edges per block ----
        const int e = (bid >> 1) * 256 + (int)threadIdx.x;
        if (e < kEdges) {
            const int d = edst[e];
            const int slot = atomicAdd(&cursor[d], 1);
            if (slot < kStride) csr_src[(size_t)d * kStride + slot] = esrc[e];
        }
        return;
    }

    // ---- gemm role ----
    const int strip = (bid < kPairBlocks) ? (bid >> 1)
                                          : (kFillBlocks + (bid - kPairBlocks));
    const int quad  = threadIdx.x >> 6;         // 0..3 (64-col quarter)
    const int lane  = threadIdx.x & 63;
    const int m  = lane & 15;
    const int kg = lane >> 4;                   // 0..3
    const long row0 = (long)strip * 16;

    const float* hrow = H + (row0 + m) * kD + kg * 8;

    f32x4 acc[4];
#pragma unroll
    for (int i = 0; i < 4; ++i) acc[i] = (f32x4){0.f, 0.f, 0.f, 0.f};

#pragma unroll
    for (int t = 0; t < 4; ++t) {               // K steps of 32
        const float4 f0 = *reinterpret_cast<const float4*>(hrow + t * 32);
        const float4 f1 = *reinterpret_cast<const float4*>(hrow + t * 32 + 4);
        short8 a;
        a[0] = f2bf(f0.x); a[1] = f2bf(f0.y); a[2] = f2bf(f0.z); a[3] = f2bf(f0.w);
        a[4] = f2bf(f1.x); a[5] = f2bf(f1.y); a[6] = f2bf(f1.z); a[7] = f2bf(f1.w);

        // B row for global col c is BT row c;  c = quad*64 + n*16 + m
        const short* bbase = BT + ((size_t)quad * 64 + m) * kD + t * 32 + kg * 8;
#pragma unroll
        for (int n = 0; n < 4; ++n) {
            const short8 b = *reinterpret_cast<const short8*>(bbase + (size_t)n * 16 * kD);
            acc[n] = __builtin_amdgcn_mfma_f32_16x16x32_bf16(a, b, acc[n], 0, 0, 0);
        }
    }

    if (quad < 2) {                             // hu -> d_out (f32)
#pragma unroll
        for (int n = 0; n < 4; ++n) {
            const int c = quad * 64 + n * 16 + m;
#pragma unroll
            for (int j = 0; j < 4; ++j)
                hu[(row0 + kg * 4 + j) * kD + c] = acc[n][j];
        }
    } else {                                    // hv -> ws (bf16)
#pragma unroll
        for (int n = 0; n < 4; ++n) {
            const int c = (quad - 2) * 64 + n * 16 + m;
#pragma unroll
            for (int j = 0; j < 4; ++j)
                hvb[(row0 + kg * 4 + j) * kD + c] = (unsigned short)f2bf(acc[n][j]);
        }
    }
}

// ---------------------------------------------------------------------------
// Kernel 2: aggregation + ReLU.  One wave per node.  The whole neighbor list
// is fetched with ONE per-lane vector load (seg[lane]); readlane broadcasts
// each index (uniform loop var -> SGPR).  Unroll x4 for MLP.  hv rows are
// bf16: each lane loads one dword (features 2*lane, 2*lane+1), expands to f32
// by bit-shift (exact).  out already holds hu (f32); ReLU fused.
// ---------------------------------------------------------------------------
__global__ __launch_bounds__(256) void aggregate_relu(const unsigned int* __restrict__ hvb,
                                                      const int* __restrict__ cursor,
                                                      const int* __restrict__ csr_src,
                                                      float* __restrict__ out) {
    const int wid  = (int)((blockIdx.x * (long)blockDim.x + threadIdx.x) >> 6);
    const int lane = threadIdx.x & 63;
    if (wid >= kNodes) return;

    const int deg = min(cursor[wid], kStride);          // wave-uniform
    const int v   = csr_src[(size_t)wid * kStride + lane];  // whole list, 1 load

    float a0 = 0.f, a1 = 0.f;
    int e = 0;
    for (; e + 4 <= deg; e += 4) {
        const int s0 = __builtin_amdgcn_readlane(v, e);
        const int s1 = __builtin_amdgcn_readlane(v, e + 1);
        const int s2 = __builtin_amdgcn_readlane(v, e + 2);
        const int s3 = __builtin_amdgcn_readlane(v, e + 3);
        const unsigned int w0 = hvb[(size_t)s0 * 64 + lane];
        const unsigned int w1 = hvb[(size_t)s1 * 64 + lane];
        const unsigned int w2 = hvb[(size_t)s2 * 64 + lane];
        const unsigned int w3 = hvb[(size_t)s3 * 64 + lane];
        a0 += __uint_as_float(w0 << 16) + __uint_as_float(w1 << 16)
            + __uint_as_float(w2 << 16) + __uint_as_float(w3 << 16);
        a1 += __uint_as_float(w0 & 0xffff0000u) + __uint_as_float(w1 & 0xffff0000u)
            + __uint_as_float(w2 & 0xffff0000u) + __uint_as_float(w3 & 0xffff0000u);
    }
    for (; e < deg; ++e) {
        const int s = __builtin_amdgcn_readlane(v, e);
        const unsigned int w = hvb[(size_t)s * 64 + lane];
        a0 += __uint_as_float(w << 16);
        a1 += __uint_as_float(w & 0xffff0000u);
    }

    float2* out2 = reinterpret_cast<float2*>(out);
    float2 o = out2[(size_t)wid * 64 + lane];
    o.x = fmaxf(o.x + a0, 0.f);
    o.y = fmaxf(o.y + a1, 0.f);
    out2[(size_t)wid * 64 + lane] = o;
}

extern "C" void kernel_launch(void* const* d_in, const int* in_sizes, int n_in,
                              void* d_out, int out_size, void* d_ws, size_t ws_size,
                              hipStream_t stream) {
    const float* H    = (const float*)d_in[0];
    const float* U    = (const float*)d_in[1];
    const float* V    = (const float*)d_in[2];
    const int*   esrc = (const int*)d_in[3];
    const int*   edst = (const int*)d_in[4];

    float* out = (float*)d_out;

    // Workspace layout (~25.9 MB; proven available)
    char* p = (char*)d_ws;
    unsigned short* hvb = (unsigned short*)p;  p += (size_t)kNodes * kD * 2;        // 12.8 MB
    short* BT           = (short*)p;           p += (size_t)256 * kD * 2;           // 64 KB
    int*   cursor       = (int*)p;             p += (size_t)kNodes * 4;             // 200 KB
    int*   csr_src      = (int*)p;             p += (size_t)kNodes * kStride * 4;   // 12.8 MB

    hipMemsetAsync(cursor, 0, (size_t)kNodes * sizeof(int), stream);

    // B pack (gemm dependency, ~2us)
    pack_b<<<256, 128, 0, stream>>>(U, V, BT);

    // Fused: MFMA dual GEMM + CSR fill, block-role interleaved
    gemm_fill<<<kTotalBlocks, 256, 0, stream>>>(H, BT, esrc, edst,
                                                out, hvb, cursor, csr_src);

    // Aggregate + fused ReLU
    aggregate_relu<<<(kNodes * 64 + 255) / 256, 256, 0, stream>>>(
        (const unsigned int*)hvb, cursor, csr_src, out);
}

// Round 6
// 99.242 us; speedup vs baseline: 3.2180x; 1.0470x over previous
//
#include <hip/hip_runtime.h>
#include <hip/hip_bf16.h>

constexpr int kNodes  = 50000;
constexpr int kEdges  = 600000;
constexpr int kD      = 128;
constexpr int kStrips = kNodes / 16;               // 3125 gemm strips
constexpr int kStride = 64;                        // CSR segment capacity (max deg ~35)
constexpr int kFillBlocks = (kEdges + 255) / 256;  // 2344 fill blocks
constexpr int kPairBlocks = 2 * kFillBlocks;       // 4688 interleaved region
constexpr int kTotalBlocks = kStrips + kFillBlocks;// 5469

typedef __attribute__((ext_vector_type(8))) short  short8;   // 8 bf16 (A/B frag)
typedef __attribute__((ext_vector_type(4))) float  f32x4;    // C/D frag

__device__ __forceinline__ short f2bf(float x) {
    __hip_bfloat16 h = __float2bfloat16(x);                   // RTNE
    return __builtin_bit_cast(short, h);
}

// ---------------------------------------------------------------------------
// Prep: pack B^T = [U | V]^T as bf16 (BT[n][k]) AND zero the CSR cursor.
// 128 blocks x 512 threads = 65536 >= max(32768 BT elems, 50000 cursors).
// ---------------------------------------------------------------------------
__global__ __launch_bounds__(512) void pack_init(const float* __restrict__ U,
                                                 const float* __restrict__ V,
                                                 short* __restrict__ BT,
                                                 int* __restrict__ cursor) {
    const int g = blockIdx.x * 512 + threadIdx.x;
    if (g < 256 * kD) {
        const int n = g >> 7;          // 0..255
        const int k = g & 127;
        const float x = (n < kD) ? U[k * kD + n] : V[k * kD + (n - kD)];
        BT[n * kD + k] = f2bf(x);
    }
    if (g < kNodes) cursor[g] = 0;
}

// ---------------------------------------------------------------------------
// FUSED kernel: MFMA dual GEMM + CSR fill (disjoint in/out sets), block-role
// interleaved.  gemm role: wave = 16 rows x 64 cols (4 n-tiles).
//   quarters 0,1 -> hu as bf16 packed into the FIRST 256B of each d_out row
//   (self-contained staging: aggregate reads row u's hub then overwrites
//   row u -- no cross-node hazard);
//   quarters 2,3 -> hv as bf16 into ws.
// mfma_f32_16x16x32_bf16: A lane m=l&15 reads 8 contiguous k at octet l>>4;
// C/D: col=l&15, row=(l>>4)*4+j  (m89-verified mapping).
// fill role: slot = atomicAdd(&cursor[dst],1); csr16[dst*64+slot] = (u16)src.
// ~600K random-line device atomics ~= 31us floor (8 line-RMW/cycle model).
// ---------------------------------------------------------------------------
__global__ __launch_bounds__(256) void gemm_fill(const float* __restrict__ H,
                                                 const short* __restrict__ BT,
                                                 const int* __restrict__ esrc,
                                                 const int* __restrict__ edst,
                                                 unsigned short* __restrict__ outb, // d_out as u16
                                                 unsigned short* __restrict__ hvb,
                                                 int* __restrict__ cursor,
                                                 unsigned short* __restrict__ csr16) {
    const int bid = blockIdx.x;

    if (bid < kPairBlocks && (bid & 1)) {
        // ---- fill role: 256 edges per block ----
        const int e = (bid >> 1) * 256 + (int)threadIdx.x;
        if (e < kEdges) {
            const int d = edst[e];
            const int slot = atomicAdd(&cursor[d], 1);
            if (slot < kStride)
                csr16[(size_t)d * kStride + slot] = (unsigned short)esrc[e];
        }
        return;
    }

    // ---- gemm role ----
    const int strip = (bid < kPairBlocks) ? (bid >> 1)
                                          : (kFillBlocks + (bid - kPairBlocks));
    const int quad  = threadIdx.x >> 6;         // 0..3 (64-col quarter)
    const int lane  = threadIdx.x & 63;
    const int m  = lane & 15;
    const int kg = lane >> 4;                   // 0..3
    const long row0 = (long)strip * 16;

    const float* hrow = H + (row0 + m) * kD + kg * 8;

    f32x4 acc[4];
#pragma unroll
    for (int i = 0; i < 4; ++i) acc[i] = (f32x4){0.f, 0.f, 0.f, 0.f};

#pragma unroll
    for (int t = 0; t < 4; ++t) {               // K steps of 32
        const float4 f0 = *reinterpret_cast<const float4*>(hrow + t * 32);
        const float4 f1 = *reinterpret_cast<const float4*>(hrow + t * 32 + 4);
        short8 a;
        a[0] = f2bf(f0.x); a[1] = f2bf(f0.y); a[2] = f2bf(f0.z); a[3] = f2bf(f0.w);
        a[4] = f2bf(f1.x); a[5] = f2bf(f1.y); a[6] = f2bf(f1.z); a[7] = f2bf(f1.w);

        // B row for global col c is BT row c;  c = quad*64 + n*16 + m
        const short* bbase = BT + ((size_t)quad * 64 + m) * kD + t * 32 + kg * 8;
#pragma unroll
        for (int n = 0; n < 4; ++n) {
            const short8 b = *reinterpret_cast<const short8*>(bbase + (size_t)n * 16 * kD);
            acc[n] = __builtin_amdgcn_mfma_f32_16x16x32_bf16(a, b, acc[n], 0, 0, 0);
        }
    }

    if (quad < 2) {                             // hu -> d_out rows, bf16 in first 256B
        // out row r occupies ushort [r*256, r*256+256); col c at r*256 + c
#pragma unroll
        for (int n = 0; n < 4; ++n) {
            const int c = quad * 64 + n * 16 + m;
#pragma unroll
            for (int j = 0; j < 4; ++j)
                outb[(size_t)(row0 + kg * 4 + j) * 256 + c] = (unsigned short)f2bf(acc[n][j]);
        }
    } else {                                    // hv -> ws (bf16)
#pragma unroll
        for (int n = 0; n < 4; ++n) {
            const int c = (quad - 2) * 64 + n * 16 + m;
#pragma unroll
            for (int j = 0; j < 4; ++j)
                hvb[(size_t)(row0 + kg * 4 + j) * kD + c] = (unsigned short)f2bf(acc[n][j]);
        }
    }
}

// ---------------------------------------------------------------------------
// Kernel 2: aggregation + ReLU.  One wave per node.  Neighbor list (ushort,
// 128B) fetched by lanes 0..31 as one dword each; readlane broadcasts packed
// pairs.  hv rows bf16: one dword per lane = features 2*lane, 2*lane+1.
// hu read as bf16 from d_out row's first 256B (dword lane), then the full
// f32 row is written over it (per-lane load completes before store issues;
// each wave only touches its own row).
// ---------------------------------------------------------------------------
__global__ __launch_bounds__(256) void aggregate_relu(const unsigned int* __restrict__ hvb,
                                                      const int* __restrict__ cursor,
                                                      const unsigned short* __restrict__ csr16,
                                                      float* __restrict__ out) {
    const int wid  = (int)((blockIdx.x * (long)blockDim.x + threadIdx.x) >> 6);
    const int lane = threadIdx.x & 63;
    if (wid >= kNodes) return;

    const int deg = min(cursor[wid], kStride);          // wave-uniform
    const unsigned int w =
        reinterpret_cast<const unsigned int*>(csr16 + (size_t)wid * kStride)[lane & 31];

    // hu (bf16) from this node's own output row, dword `lane` = cols 2l,2l+1
    const unsigned int hw = reinterpret_cast<const unsigned int*>(out)[(size_t)wid * 128 + lane];

    float a0 = 0.f, a1 = 0.f;
    int e = 0;
    for (; e + 4 <= deg; e += 4) {
        const int p0 = __builtin_amdgcn_readlane(w, e >> 1);
        const int p1 = __builtin_amdgcn_readlane(w, (e >> 1) + 1);
        const int s0 = p0 & 0xffff, s1 = (p0 >> 16) & 0xffff;
        const int s2 = p1 & 0xffff, s3 = (p1 >> 16) & 0xffff;
        const unsigned int w0 = hvb[(size_t)s0 * 64 + lane];
        const unsigned int w1 = hvb[(size_t)s1 * 64 + lane];
        const unsigned int w2 = hvb[(size_t)s2 * 64 + lane];
        const unsigned int w3 = hvb[(size_t)s3 * 64 + lane];
        a0 += __uint_as_float(w0 << 16) + __uint_as_float(w1 << 16)
            + __uint_as_float(w2 << 16) + __uint_as_float(w3 << 16);
        a1 += __uint_as_float(w0 & 0xffff0000u) + __uint_as_float(w1 & 0xffff0000u)
            + __uint_as_float(w2 & 0xffff0000u) + __uint_as_float(w3 & 0xffff0000u);
    }
    for (; e < deg; ++e) {
        const int p = __builtin_amdgcn_readlane(w, e >> 1);
        const int s = (e & 1) ? ((p >> 16) & 0xffff) : (p & 0xffff);
        const unsigned int wv = hvb[(size_t)s * 64 + lane];
        a0 += __uint_as_float(wv << 16);
        a1 += __uint_as_float(wv & 0xffff0000u);
    }

    const float b0 = __uint_as_float(hw << 16);
    const float b1 = __uint_as_float(hw & 0xffff0000u);

    float2* out2 = reinterpret_cast<float2*>(out);
    float2 o;
    o.x = fmaxf(b0 + a0, 0.f);
    o.y = fmaxf(b1 + a1, 0.f);
    out2[(size_t)wid * 64 + lane] = o;
}

extern "C" void kernel_launch(void* const* d_in, const int* in_sizes, int n_in,
                              void* d_out, int out_size, void* d_ws, size_t ws_size,
                              hipStream_t stream) {
    const float* H    = (const float*)d_in[0];
    const float* U    = (const float*)d_in[1];
    const float* V    = (const float*)d_in[2];
    const int*   esrc = (const int*)d_in[3];
    const int*   edst = (const int*)d_in[4];

    float* out = (float*)d_out;

    // Workspace layout (~19.5 MB; 25.9 MB proven available in R5)
    char* p = (char*)d_ws;
    unsigned short* hvb  = (unsigned short*)p;  p += (size_t)kNodes * kD * 2;          // 12.8 MB
    short*          BT   = (short*)p;           p += (size_t)256 * kD * 2;             // 64 KB
    int*            cur  = (int*)p;             p += (size_t)kNodes * 4;               // 200 KB
    unsigned short* csr16= (unsigned short*)p;  p += (size_t)kNodes * kStride * 2;     // 6.4 MB

    // B pack + cursor zeroing in one dispatch
    pack_init<<<128, 512, 0, stream>>>(U, V, BT, cur);

    // Fused: MFMA dual GEMM (hu bf16 -> d_out rows, hv bf16 -> ws) + CSR fill
    gemm_fill<<<kTotalBlocks, 256, 0, stream>>>(H, BT, esrc, edst,
                                                (unsigned short*)d_out, hvb, cur, csr16);

    // Aggregate + fused ReLU (reads hub from d_out rows, overwrites with f32)
    aggregate_relu<<<(kNodes * 64 + 255) / 256, 256, 0, stream>>>(
        (const unsigned int*)hvb, cur, csr16, out);
}

// Round 7
// 73.993 us; speedup vs baseline: 4.3160x; 1.3412x over previous
//
#include <hip/hip_runtime.h>
#include <hip/hip_bf16.h>

constexpr int kNodes  = 50000;
constexpr int kEdges  = 600000;
constexpr int kD      = 128;
constexpr int kStrips = kNodes / 16;               // 3125 gemm strips
constexpr int kStride = 64;                        // CSR segment capacity (max deg ~35)
constexpr int kFillBlocks = (kEdges + 255) / 256;  // 2344 fill blocks
constexpr int kPairBlocks = 2 * kFillBlocks;       // 4688 interleaved region
constexpr int kTotalBlocks = kStrips + kFillBlocks;// 5469

typedef __attribute__((ext_vector_type(8))) short  short8;   // 8 bf16 (A/B frag)
typedef __attribute__((ext_vector_type(4))) float  f32x4;    // C/D frag

__device__ __forceinline__ short f2bf(float x) {
    __hip_bfloat16 h = __float2bfloat16(x);                   // RTNE
    return __builtin_bit_cast(short, h);
}

// ---------------------------------------------------------------------------
// Prep: pack B^T = [U | V]^T as bf16 in FRAGMENT-MAJOR layout + zero cursor.
// BTf element for (global col c, k): q=c>>6, n=(c>>4)&3, m=c&15, t=k>>5,
// kg=(k>>3)&3, ko=k&7, lane=kg*16+m ->
//   BTf[ (((q*4+n)*4+t)*64 + lane)*8 + ko ]
// so in the gemm each (n,t) B-frag is ONE dwordx4 at base+lane*16B — dense,
// per-lane-contiguous, no transaction amplification.
// ---------------------------------------------------------------------------
__global__ __launch_bounds__(512) void pack_init(const float* __restrict__ U,
                                                 const float* __restrict__ V,
                                                 short* __restrict__ BTf,
                                                 int* __restrict__ cursor) {
    const int g = blockIdx.x * 512 + threadIdx.x;
    if (g < 256 * kD) {
        const int c = g >> 7;          // 0..255 (global output col)
        const int k = g & 127;
        const float x = (c < kD) ? U[k * kD + c] : V[k * kD + (c - kD)];
        const int q  = c >> 6;
        const int n  = (c >> 4) & 3;
        const int m  = c & 15;
        const int t  = k >> 5;
        const int kg = (k >> 3) & 3;
        const int ko = k & 7;
        const int lane = kg * 16 + m;
        BTf[((((q * 4 + n) * 4 + t) * 64 + lane) << 3) + ko] = f2bf(x);
    }
    if (g < kNodes) cursor[g] = 0;
}

// ---------------------------------------------------------------------------
// FUSED kernel: MFMA dual GEMM + CSR fill, block-role interleaved.
//
// gemm role (R7 restructure): issue ALL loads up front — 8x dwordx4 from H
// (lane's 32B x 4 k-steps) + 16x dwordx4 from BTf (frag-major) — then one
// wait, convert, and 16 dependency-free MFMAs.  Registers are the prefetch
// buffer (~130 VGPR intended): kills the load->mfma round-trip chain that
// made R3-R6 invariant at ~48us (52 VGPR = JIT-scheduled loads, ~19K
// cycles/wave of serialized L2 latency).
//   quarters 0,1 -> hu as bf16 into first 256B of each d_out row;
//   quarters 2,3 -> hv as bf16 into ws.
// mfma_f32_16x16x32_bf16: A lane m=l&15 reads 8 contiguous k at octet l>>4;
// C/D: col=l&15, row=(l>>4)*4+j  (m89-verified mapping).
//
// fill role: slot = atomicAdd(&cursor[dst],1); csr16[dst*64+slot] = (u16)src.
// ---------------------------------------------------------------------------
__global__ __launch_bounds__(256) void gemm_fill(const float* __restrict__ H,
                                                 const short* __restrict__ BTf,
                                                 const int* __restrict__ esrc,
                                                 const int* __restrict__ edst,
                                                 unsigned short* __restrict__ outb, // d_out as u16
                                                 unsigned short* __restrict__ hvb,
                                                 int* __restrict__ cursor,
                                                 unsigned short* __restrict__ csr16) {
    const int bid = blockIdx.x;

    if (bid < kPairBlocks && (bid & 1)) {
        // ---- fill role: 256 edges per block ----
        const int e = (bid >> 1) * 256 + (int)threadIdx.x;
        if (e < kEdges) {
            const int d = edst[e];
            const int slot = atomicAdd(&cursor[d], 1);
            if (slot < kStride)
                csr16[(size_t)d * kStride + slot] = (unsigned short)esrc[e];
        }
        return;
    }

    // ---- gemm role ----
    const int strip = (bid < kPairBlocks) ? (bid >> 1)
                                          : (kFillBlocks + (bid - kPairBlocks));
    const int quad  = threadIdx.x >> 6;         // 0..3 (64-col quarter)
    const int lane  = threadIdx.x & 63;
    const int m  = lane & 15;
    const int kg = lane >> 4;                   // 0..3
    const long row0 = (long)strip * 16;

    // ---- issue ALL loads up front (24 outstanding; vmcnt handles it) ----
    const float* hbase = H + (row0 + m) * kD + kg * 8;
    float4 ha[4][2];
#pragma unroll
    for (int t = 0; t < 4; ++t) {
        ha[t][0] = *reinterpret_cast<const float4*>(hbase + t * 32);
        ha[t][1] = *reinterpret_cast<const float4*>(hbase + t * 32 + 4);
    }

    const short8* bq = reinterpret_cast<const short8*>(BTf)
                     + ((size_t)quad * 16) * 64 + lane;        // frag (q,0,0), this lane
    short8 bf[4][4];
#pragma unroll
    for (int n = 0; n < 4; ++n)
#pragma unroll
        for (int t = 0; t < 4; ++t)
            bf[n][t] = bq[(n * 4 + t) * 64];                   // dwordx4, imm-offset

    // ---- convert A to bf16 frags ----
    short8 a[4];
#pragma unroll
    for (int t = 0; t < 4; ++t) {
        a[t][0] = f2bf(ha[t][0].x); a[t][1] = f2bf(ha[t][0].y);
        a[t][2] = f2bf(ha[t][0].z); a[t][3] = f2bf(ha[t][0].w);
        a[t][4] = f2bf(ha[t][1].x); a[t][5] = f2bf(ha[t][1].y);
        a[t][6] = f2bf(ha[t][1].z); a[t][7] = f2bf(ha[t][1].w);
    }

    // ---- 16 dependency-free MFMAs (4 acc chains of depth 4) ----
    f32x4 acc[4];
#pragma unroll
    for (int i = 0; i < 4; ++i) acc[i] = (f32x4){0.f, 0.f, 0.f, 0.f};
#pragma unroll
    for (int t = 0; t < 4; ++t)
#pragma unroll
        for (int n = 0; n < 4; ++n)
            acc[n] = __builtin_amdgcn_mfma_f32_16x16x32_bf16(a[t], bf[n][t], acc[n], 0, 0, 0);

    // ---- epilogue ----
    if (quad < 2) {                             // hu -> d_out rows, bf16 in first 256B
#pragma unroll
        for (int n = 0; n < 4; ++n) {
            const int c = quad * 64 + n * 16 + m;
#pragma unroll
            for (int j = 0; j < 4; ++j)
                outb[(size_t)(row0 + kg * 4 + j) * 256 + c] = (unsigned short)f2bf(acc[n][j]);
        }
    } else {                                    // hv -> ws (bf16)
#pragma unroll
        for (int n = 0; n < 4; ++n) {
            const int c = (quad - 2) * 64 + n * 16 + m;
#pragma unroll
            for (int j = 0; j < 4; ++j)
                hvb[(size_t)(row0 + kg * 4 + j) * kD + c] = (unsigned short)f2bf(acc[n][j]);
        }
    }
}

// ---------------------------------------------------------------------------
// Kernel 2: aggregation + ReLU.  One wave per node; neighbor list (ushort,
// 128B) fetched as one dword per lane (lanes 0..31); readlane broadcasts
// packed index pairs.  hv rows bf16: one dword per lane = features 2l,2l+1.
// hu read as bf16 from d_out row's first 256B, then the full f32 row is
// written over it (wave only touches its own row).
// ---------------------------------------------------------------------------
__global__ __launch_bounds__(256) void aggregate_relu(const unsigned int* __restrict__ hvb,
                                                      const int* __restrict__ cursor,
                                                      const unsigned short* __restrict__ csr16,
                                                      float* __restrict__ out) {
    const int wid  = (int)((blockIdx.x * (long)blockDim.x + threadIdx.x) >> 6);
    const int lane = threadIdx.x & 63;
    if (wid >= kNodes) return;

    const int deg = min(cursor[wid], kStride);          // wave-uniform
    const unsigned int w =
        reinterpret_cast<const unsigned int*>(csr16 + (size_t)wid * kStride)[lane & 31];

    // hu (bf16) from this node's own output row, dword `lane` = cols 2l,2l+1
    const unsigned int hw = reinterpret_cast<const unsigned int*>(out)[(size_t)wid * 128 + lane];

    float a0 = 0.f, a1 = 0.f;
    int e = 0;
    for (; e + 4 <= deg; e += 4) {
        const int p0 = __builtin_amdgcn_readlane(w, e >> 1);
        const int p1 = __builtin_amdgcn_readlane(w, (e >> 1) + 1);
        const int s0 = p0 & 0xffff, s1 = (p0 >> 16) & 0xffff;
        const int s2 = p1 & 0xffff, s3 = (p1 >> 16) & 0xffff;
        const unsigned int w0 = hvb[(size_t)s0 * 64 + lane];
        const unsigned int w1 = hvb[(size_t)s1 * 64 + lane];
        const unsigned int w2 = hvb[(size_t)s2 * 64 + lane];
        const unsigned int w3 = hvb[(size_t)s3 * 64 + lane];
        a0 += __uint_as_float(w0 << 16) + __uint_as_float(w1 << 16)
            + __uint_as_float(w2 << 16) + __uint_as_float(w3 << 16);
        a1 += __uint_as_float(w0 & 0xffff0000u) + __uint_as_float(w1 & 0xffff0000u)
            + __uint_as_float(w2 & 0xffff0000u) + __uint_as_float(w3 & 0xffff0000u);
    }
    for (; e < deg; ++e) {
        const int p = __builtin_amdgcn_readlane(w, e >> 1);
        const int s = (e & 1) ? ((p >> 16) & 0xffff) : (p & 0xffff);
        const unsigned int wv = hvb[(size_t)s * 64 + lane];
        a0 += __uint_as_float(wv << 16);
        a1 += __uint_as_float(wv & 0xffff0000u);
    }

    const float b0 = __uint_as_float(hw << 16);
    const float b1 = __uint_as_float(hw & 0xffff0000u);

    float2* out2 = reinterpret_cast<float2*>(out);
    float2 o;
    o.x = fmaxf(b0 + a0, 0.f);
    o.y = fmaxf(b1 + a1, 0.f);
    out2[(size_t)wid * 64 + lane] = o;
}

extern "C" void kernel_launch(void* const* d_in, const int* in_sizes, int n_in,
                              void* d_out, int out_size, void* d_ws, size_t ws_size,
                              hipStream_t stream) {
    const float* H    = (const float*)d_in[0];
    const float* U    = (const float*)d_in[1];
    const float* V    = (const float*)d_in[2];
    const int*   esrc = (const int*)d_in[3];
    const int*   edst = (const int*)d_in[4];

    float* out = (float*)d_out;

    // Workspace layout (~19.5 MB; proven available)
    char* p = (char*)d_ws;
    unsigned short* hvb  = (unsigned short*)p;  p += (size_t)kNodes * kD * 2;          // 12.8 MB
    short*          BTf  = (short*)p;           p += (size_t)256 * kD * 2;             // 64 KB
    int*            cur  = (int*)p;             p += (size_t)kNodes * 4;               // 200 KB
    unsigned short* csr16= (unsigned short*)p;  p += (size_t)kNodes * kStride * 2;     // 6.4 MB

    // B pack (frag-major) + cursor zeroing in one dispatch
    pack_init<<<128, 512, 0, stream>>>(U, V, BTf, cur);

    // Fused: MFMA dual GEMM (all-upfront loads) + CSR fill
    gemm_fill<<<kTotalBlocks, 256, 0, stream>>>(H, BTf, esrc, edst,
                                                (unsigned short*)d_out, hvb, cur, csr16);

    // Aggregate + fused ReLU (reads hub from d_out rows, overwrites with f32)
    aggregate_relu<<<(kNodes * 64 + 255) / 256, 256, 0, stream>>>(
        (const unsigned int*)hvb, cur, csr16, out);
}